// Round 1
// baseline (4510.944 us; speedup 1.0000x reference)
//
#include <hip/hip_runtime.h>
#include <math.h>

// ---------------------------------------------------------------------------
// GraphConv GNN: x1 = relu(scatter(x)*W1rel + x*W1root + b1)
//                x2 = relu(scatter(x1)*W2rel + x1*W2root + b2)
//                out = log_softmax([x1|x2] @ w_lin + b_lin)
// Round 0: correct fp32 pipeline. 5 stages on one stream.
// ---------------------------------------------------------------------------

// ---- Stage: scatter-add  agg[dst,c] += feat[src,c] * w[e] ------------------
template <int C>
__global__ __launch_bounds__(256) void scatter_kernel(
    const float* __restrict__ feat,   // [N, C]
    const int*   __restrict__ ei,     // [2, E] (row 0 = src, row 1 = dst)
    const float* __restrict__ ew,     // [E]
    float*       __restrict__ agg,    // [N, C], pre-zeroed
    int E)
{
    constexpr int C4 = C / 4;
    long long idx   = (long long)blockIdx.x * blockDim.x + threadIdx.x;
    long long total = (long long)E * C4;
    if (idx >= total) return;
    int e  = (int)(idx >> (C == 128 ? 5 : 6));   // idx / C4
    int c4 = (int)(idx & (C4 - 1));              // idx % C4
    int src = ei[e];
    int dst = ei[E + e];
    float w = ew[e];
    const float4 v = *(const float4*)&feat[(long long)src * C + c4 * 4];
    float* a = &agg[(long long)dst * C + c4 * 4];
    atomicAdd(a + 0, v.x * w);
    atomicAdd(a + 1, v.y * w);
    atomicAdd(a + 2, v.z * w);
    atomicAdd(a + 3, v.w * w);
}

// ---- Stage: C = relu(A0 @ W0 + A1 @ W1 + bias) ----------------------------
// A0:[n,K0] A1:[n,K1] W0:[K0,NC] W1:[K1,NC] row-major, NC multiple of 64.
#define BM 64
#define BN 64
#define BK 16

__global__ __launch_bounds__(256) void gemm2_bias_relu(
    const float* __restrict__ A0, const float* __restrict__ A1,
    const float* __restrict__ W0, const float* __restrict__ W1,
    const float* __restrict__ bias,
    float* __restrict__ Cm,
    int n, int K0, int K1, int NC)
{
    __shared__ float As[BM][BK];
    __shared__ float Bs[BK][BN];

    const int ntN  = NC / BN;
    const int bm   = blockIdx.x / ntN;
    const int bn   = blockIdx.x % ntN;
    const int row0 = bm * BM;
    const int col0 = bn * BN;

    const int t  = threadIdx.x;
    const int tx = t % 16;      // N-dir
    const int ty = t / 16;      // M-dir

    float acc[4][4] = {};

    for (int seg = 0; seg < 2; ++seg) {
        const float* A = seg ? A1 : A0;
        const float* W = seg ? W1 : W0;
        const int    K = seg ? K1 : K0;
        for (int k0 = 0; k0 < K; k0 += BK) {
            // A tile: 64x16, one float4 per thread
            {
                int r  = t >> 2;            // 0..63
                int c4 = (t & 3) * 4;       // 0,4,8,12
                int gr = row0 + r;
                float4 av = make_float4(0.f, 0.f, 0.f, 0.f);
                if (gr < n) av = *(const float4*)&A[(long long)gr * K + k0 + c4];
                *(float4*)&As[r][c4] = av;
            }
            // B tile: 16x64, one float4 per thread
            {
                int rb = t >> 4;            // 0..15
                int cb = (t & 15) * 4;      // 0..60
                float4 bv = *(const float4*)&W[(long long)(k0 + rb) * NC + col0 + cb];
                *(float4*)&Bs[rb][cb] = bv;
            }
            __syncthreads();
#pragma unroll
            for (int kk = 0; kk < BK; ++kk) {
                float a[4], b[4];
#pragma unroll
                for (int i = 0; i < 4; ++i) a[i] = As[ty * 4 + i][kk];
#pragma unroll
                for (int j = 0; j < 4; ++j) b[j] = Bs[kk][tx * 4 + j];
#pragma unroll
                for (int i = 0; i < 4; ++i)
#pragma unroll
                    for (int j = 0; j < 4; ++j)
                        acc[i][j] = fmaf(a[i], b[j], acc[i][j]);
            }
            __syncthreads();
        }
    }

#pragma unroll
    for (int i = 0; i < 4; ++i) {
        int gr = row0 + ty * 4 + i;
        if (gr >= n) continue;
#pragma unroll
        for (int j = 0; j < 4; ++j) {
            int gc = col0 + tx * 4 + j;
            float v = acc[i][j] + bias[gc];
            Cm[(long long)gr * NC + gc] = fmaxf(v, 0.f);
        }
    }
}

// ---- Stage: head  out = log_softmax([x1|x2] @ w_lin + b_lin) --------------
// One 64-lane wave per node, 4 waves per block.
__global__ __launch_bounds__(256) void head_kernel(
    const float* __restrict__ x1,    // [N,256]
    const float* __restrict__ x2,    // [N,256]
    const float* __restrict__ w_lin, // [512,40]
    const float* __restrict__ b_lin, // [40]
    float* __restrict__ out,         // [N,40]
    int n)
{
    __shared__ float hsh[4][512];
    const int wave = threadIdx.x >> 6;
    const int lane = threadIdx.x & 63;
    const int node = blockIdx.x * 4 + wave;

    if (node < n) {
        for (int k = lane; k < 256; k += 64) {
            hsh[wave][k]       = x1[(long long)node * 256 + k];
            hsh[wave][256 + k] = x2[(long long)node * 256 + k];
        }
    }
    __syncthreads();

    float logit = -INFINITY;
    if (node < n && lane < 40) {
        float s = b_lin[lane];
#pragma unroll 8
        for (int k = 0; k < 512; ++k)
            s = fmaf(hsh[wave][k], w_lin[k * 40 + lane], s);
        logit = s;
    }
    // 64-lane max reduce
    float m = logit;
#pragma unroll
    for (int off = 32; off; off >>= 1) m = fmaxf(m, __shfl_xor(m, off, 64));
    float e = (lane < 40 && node < n) ? expf(logit - m) : 0.f;
    float ssum = e;
#pragma unroll
    for (int off = 32; off; off >>= 1) ssum += __shfl_xor(ssum, off, 64);

    if (node < n && lane < 40)
        out[(long long)node * 40 + lane] = logit - m - logf(ssum);
}

// ---------------------------------------------------------------------------
extern "C" void kernel_launch(void* const* d_in, const int* in_sizes, int n_in,
                              void* d_out, int out_size, void* d_ws, size_t ws_size,
                              hipStream_t stream)
{
    const float* x       = (const float*)d_in[0];
    const int*   ei      = (const int*)  d_in[1];
    const float* ew      = (const float*)d_in[2];
    const float* w1_rel  = (const float*)d_in[3];
    const float* b1      = (const float*)d_in[4];
    const float* w1_root = (const float*)d_in[5];
    const float* w2_rel  = (const float*)d_in[6];
    const float* b2      = (const float*)d_in[7];
    const float* w2_root = (const float*)d_in[8];
    const float* w_lin   = (const float*)d_in[9];
    const float* b_lin   = (const float*)d_in[10];
    float* out = (float*)d_out;

    const int N = in_sizes[0] / 128;   // 50000
    const int E = in_sizes[2];         // 800000

    float* ws   = (float*)d_ws;
    float* agg1 = ws;                          // [N,128]
    float* x1   = ws + (size_t)N * 128;        // [N,256]
    float* agg2 = ws + (size_t)N * 384;        // [N,256]
    float* x2   = ws + (size_t)N * 640;        // [N,256]

    hipMemsetAsync(agg1, 0, (size_t)N * 128 * sizeof(float), stream);
    hipMemsetAsync(agg2, 0, (size_t)N * 256 * sizeof(float), stream);

    // layer 1 scatter: E * 32 threads
    {
        long long total  = (long long)E * 32;
        int       blocks = (int)((total + 255) / 256);
        scatter_kernel<128><<<blocks, 256, 0, stream>>>(x, ei, ew, agg1, E);
    }
    // layer 1 gemm: x1 = relu(agg1@w1_rel + x@w1_root + b1)
    {
        int gm = (N + BM - 1) / BM;
        gemm2_bias_relu<<<gm * (256 / BN), 256, 0, stream>>>(
            agg1, x, w1_rel, w1_root, b1, x1, N, 128, 128, 256);
    }
    // layer 2 scatter: E * 64 threads
    {
        long long total  = (long long)E * 64;
        int       blocks = (int)((total + 255) / 256);
        scatter_kernel<256><<<blocks, 256, 0, stream>>>(x1, ei, ew, agg2, E);
    }
    // layer 2 gemm: x2 = relu(agg2@w2_rel + x1@w2_root + b2)
    {
        int gm = (N + BM - 1) / BM;
        gemm2_bias_relu<<<gm * (256 / BN), 256, 0, stream>>>(
            agg2, x1, w2_rel, w2_root, b2, x2, N, 256, 256, 256);
    }
    // head
    {
        int blocks = (N + 3) / 4;
        head_kernel<<<blocks, 256, 0, stream>>>(x1, x2, w_lin, b_lin, out, N);
    }
}

// Round 2
// 887.220 us; speedup vs baseline: 5.0844x; 5.0844x over previous
//
#include <hip/hip_runtime.h>
#include <math.h>

// ---------------------------------------------------------------------------
// GraphConv GNN, round 1: CSR-gather instead of atomic scatter.
// Pipeline: build CSR (count/scan/fill) -> gather L1 -> GEMM L1 ->
//           gather L2 -> GEMM L2 -> head.
// ---------------------------------------------------------------------------

// ---- CSR build ------------------------------------------------------------
__global__ __launch_bounds__(256) void count_kernel(
    const int* __restrict__ ei, int* __restrict__ counts, int E)
{
    int e = blockIdx.x * 256 + threadIdx.x;
    if (e < E) atomicAdd(&counts[ei[E + e]], 1);
}

// single block, 256 threads: exclusive scan counts[0..n) -> row_ptr & cursor
__global__ __launch_bounds__(256) void scan_kernel(
    const int* __restrict__ counts, int* __restrict__ row_ptr,
    int* __restrict__ cursor, int n)
{
    __shared__ int sums[256];
    const int t = threadIdx.x;
    const int chunk = (n + 255) / 256;
    const int beg = t * chunk;
    const int end = min(beg + chunk, n);
    int s = 0;
    for (int i = beg; i < end; ++i) s += counts[i];
    sums[t] = s;
    __syncthreads();
    for (int off = 1; off < 256; off <<= 1) {
        int v = (t >= off) ? sums[t - off] : 0;
        __syncthreads();
        sums[t] += v;
        __syncthreads();
    }
    int run = (t == 0) ? 0 : sums[t - 1];
    for (int i = beg; i < end; ++i) {
        row_ptr[i] = run;
        cursor[i]  = run;
        run += counts[i];
    }
    if (t == 0) row_ptr[n] = sums[255];
}

__global__ __launch_bounds__(256) void fill_kernel(
    const int* __restrict__ ei, const float* __restrict__ ew,
    int* __restrict__ cursor,
    int* __restrict__ src_sorted, float* __restrict__ w_sorted, int E)
{
    int e = blockIdx.x * 256 + threadIdx.x;
    if (e >= E) return;
    int d = ei[E + e];
    int p = atomicAdd(&cursor[d], 1);
    src_sorted[p] = ei[e];
    w_sorted[p]   = ew[e];
}

// ---- gather: agg[v,:] = sum_{e in in(v)} w_e * feat[src_e,:] --------------
// one 64-lane wave per node; V = C/64 floats per lane.
template <int C>
__global__ __launch_bounds__(256) void gather_kernel(
    const float* __restrict__ feat,
    const int*   __restrict__ src_sorted,
    const float* __restrict__ w_sorted,
    const int*   __restrict__ row_ptr,
    float*       __restrict__ agg, int n)
{
    const int gw   = (blockIdx.x * 256 + threadIdx.x) >> 6;  // node id
    const int lane = threadIdx.x & 63;
    if (gw >= n) return;
    const int beg = row_ptr[gw];
    const int end = row_ptr[gw + 1];
    constexpr int V = C / 64;
    float acc[V] = {};
    for (int e = beg; e < end; ++e) {
        int   s  = src_sorted[e];
        float wt = w_sorted[e];
        const float* fp = &feat[(size_t)s * C + lane * V];
        if constexpr (V == 4) {
            float4 v = *(const float4*)fp;
            acc[0] = fmaf(v.x, wt, acc[0]);
            acc[1] = fmaf(v.y, wt, acc[1]);
            acc[2] = fmaf(v.z, wt, acc[2]);
            acc[3] = fmaf(v.w, wt, acc[3]);
        } else {
            float2 v = *(const float2*)fp;
            acc[0] = fmaf(v.x, wt, acc[0]);
            acc[1] = fmaf(v.y, wt, acc[1]);
        }
    }
    float* op = &agg[(size_t)gw * C + lane * V];
#pragma unroll
    for (int i = 0; i < V; ++i) op[i] = acc[i];
}

// ---- GEMM: C = relu(A0 @ W0 + A1 @ W1 + bias) -----------------------------
#define BM 64
#define BN 64
#define BK 16

__global__ __launch_bounds__(256) void gemm2_bias_relu(
    const float* __restrict__ A0, const float* __restrict__ A1,
    const float* __restrict__ W0, const float* __restrict__ W1,
    const float* __restrict__ bias,
    float* __restrict__ Cm,
    int n, int K0, int K1, int NC)
{
    __shared__ float As[BM][BK];
    __shared__ float Bs[BK][BN];

    const int ntN  = NC / BN;
    const int bm   = blockIdx.x / ntN;
    const int bn   = blockIdx.x % ntN;
    const int row0 = bm * BM;
    const int col0 = bn * BN;

    const int t  = threadIdx.x;
    const int tx = t % 16;      // N-dir
    const int ty = t / 16;      // M-dir

    float acc[4][4] = {};

    for (int seg = 0; seg < 2; ++seg) {
        const float* A = seg ? A1 : A0;
        const float* W = seg ? W1 : W0;
        const int    K = seg ? K1 : K0;
        for (int k0 = 0; k0 < K; k0 += BK) {
            {
                int r  = t >> 2;
                int c4 = (t & 3) * 4;
                int gr = row0 + r;
                float4 av = make_float4(0.f, 0.f, 0.f, 0.f);
                if (gr < n) av = *(const float4*)&A[(long long)gr * K + k0 + c4];
                *(float4*)&As[r][c4] = av;
            }
            {
                int rb = t >> 4;
                int cb = (t & 15) * 4;
                float4 bv = *(const float4*)&W[(long long)(k0 + rb) * NC + col0 + cb];
                *(float4*)&Bs[rb][cb] = bv;
            }
            __syncthreads();
#pragma unroll
            for (int kk = 0; kk < BK; ++kk) {
                float a[4], b[4];
#pragma unroll
                for (int i = 0; i < 4; ++i) a[i] = As[ty * 4 + i][kk];
#pragma unroll
                for (int j = 0; j < 4; ++j) b[j] = Bs[kk][tx * 4 + j];
#pragma unroll
                for (int i = 0; i < 4; ++i)
#pragma unroll
                    for (int j = 0; j < 4; ++j)
                        acc[i][j] = fmaf(a[i], b[j], acc[i][j]);
            }
            __syncthreads();
        }
    }

#pragma unroll
    for (int i = 0; i < 4; ++i) {
        int gr = row0 + ty * 4 + i;
        if (gr >= n) continue;
#pragma unroll
        for (int j = 0; j < 4; ++j) {
            int gc = col0 + tx * 4 + j;
            float v = acc[i][j] + bias[gc];
            Cm[(long long)gr * NC + gc] = fmaxf(v, 0.f);
        }
    }
}

// ---- head: out = log_softmax([x1|x2] @ w_lin + b_lin) ---------------------
__global__ __launch_bounds__(256) void head_kernel(
    const float* __restrict__ x1,
    const float* __restrict__ x2,
    const float* __restrict__ w_lin,
    const float* __restrict__ b_lin,
    float* __restrict__ out,
    int n)
{
    __shared__ float hsh[4][512];
    const int wave = threadIdx.x >> 6;
    const int lane = threadIdx.x & 63;
    const int node = blockIdx.x * 4 + wave;

    if (node < n) {
        for (int k = lane; k < 256; k += 64) {
            hsh[wave][k]       = x1[(long long)node * 256 + k];
            hsh[wave][256 + k] = x2[(long long)node * 256 + k];
        }
    }
    __syncthreads();

    float logit = -INFINITY;
    if (node < n && lane < 40) {
        float s = b_lin[lane];
#pragma unroll 8
        for (int k = 0; k < 512; ++k)
            s = fmaf(hsh[wave][k], w_lin[k * 40 + lane], s);
        logit = s;
    }
    float m = logit;
#pragma unroll
    for (int off = 32; off; off >>= 1) m = fmaxf(m, __shfl_xor(m, off, 64));
    float e = (lane < 40 && node < n) ? expf(logit - m) : 0.f;
    float ssum = e;
#pragma unroll
    for (int off = 32; off; off >>= 1) ssum += __shfl_xor(ssum, off, 64);

    if (node < n && lane < 40)
        out[(long long)node * 40 + lane] = logit - m - logf(ssum);
}

// ---------------------------------------------------------------------------
extern "C" void kernel_launch(void* const* d_in, const int* in_sizes, int n_in,
                              void* d_out, int out_size, void* d_ws, size_t ws_size,
                              hipStream_t stream)
{
    const float* x       = (const float*)d_in[0];
    const int*   ei      = (const int*)  d_in[1];
    const float* ew      = (const float*)d_in[2];
    const float* w1_rel  = (const float*)d_in[3];
    const float* b1      = (const float*)d_in[4];
    const float* w1_root = (const float*)d_in[5];
    const float* w2_rel  = (const float*)d_in[6];
    const float* b2      = (const float*)d_in[7];
    const float* w2_root = (const float*)d_in[8];
    const float* w_lin   = (const float*)d_in[9];
    const float* b_lin   = (const float*)d_in[10];
    float* out = (float*)d_out;

    const int N = in_sizes[0] / 128;   // 50000
    const int E = in_sizes[2];         // 800000

    char* wp = (char*)d_ws;
    float* agg1 = (float*)wp;  wp += (size_t)N * 128 * 4;
    float* x1   = (float*)wp;  wp += (size_t)N * 256 * 4;
    float* agg2 = (float*)wp;  wp += (size_t)N * 256 * 4;
    float* x2   = (float*)wp;  wp += (size_t)N * 256 * 4;
    int*   counts     = (int*)wp;   wp += (size_t)N * 4;
    int*   row_ptr    = (int*)wp;   wp += (size_t)(N + 1) * 4;
    int*   cursor     = (int*)wp;   wp += (size_t)N * 4;
    int*   src_sorted = (int*)wp;   wp += (size_t)E * 4;
    float* w_sorted   = (float*)wp; wp += (size_t)E * 4;

    const int eb = (E + 255) / 256;

    // ---- CSR build (per call; deterministic up to fp-sum order) ----
    hipMemsetAsync(counts, 0, (size_t)N * 4, stream);
    count_kernel<<<eb, 256, 0, stream>>>(ei, counts, E);
    scan_kernel<<<1, 256, 0, stream>>>(counts, row_ptr, cursor, N);
    fill_kernel<<<eb, 256, 0, stream>>>(ei, ew, cursor, src_sorted, w_sorted, E);

    // ---- layer 1 ----
    {
        int blocks = (N * 64 + 255) / 256;
        gather_kernel<128><<<blocks, 256, 0, stream>>>(
            x, src_sorted, w_sorted, row_ptr, agg1, N);
    }
    {
        int gm = (N + BM - 1) / BM;
        gemm2_bias_relu<<<gm * (256 / BN), 256, 0, stream>>>(
            agg1, x, w1_rel, w1_root, b1, x1, N, 128, 128, 256);
    }
    // ---- layer 2 ----
    {
        int blocks = (N * 64 + 255) / 256;
        gather_kernel<256><<<blocks, 256, 0, stream>>>(
            x1, src_sorted, w_sorted, row_ptr, agg2, N);
    }
    {
        int gm = (N + BM - 1) / BM;
        gemm2_bias_relu<<<gm * (256 / BN), 256, 0, stream>>>(
            agg2, x1, w2_rel, w2_root, b2, x2, N, 256, 256, 256);
    }
    // ---- head ----
    {
        int blocks = (N + 3) / 4;
        head_kernel<<<blocks, 256, 0, stream>>>(x1, x2, w_lin, b_lin, out, N);
    }
}

// Round 3
// 488.554 us; speedup vs baseline: 9.2333x; 1.8160x over previous
//
#include <hip/hip_runtime.h>
#include <hip/hip_bf16.h>
#include <math.h>

// ---------------------------------------------------------------------------
// GraphConv GNN, round 2: bf16 MFMA GEMMs + bf16 gathers + fused MFMA head.
// ---------------------------------------------------------------------------

typedef __attribute__((ext_vector_type(8))) short short8;
typedef __attribute__((ext_vector_type(4))) float f32x4;

static __device__ __forceinline__ float bf2f(unsigned short u) {
    return __uint_as_float(((unsigned)u) << 16);
}

// ---- CSR build ------------------------------------------------------------
__global__ __launch_bounds__(256) void count_kernel(
    const int* __restrict__ ei, int* __restrict__ counts, int E)
{
    int e = blockIdx.x * 256 + threadIdx.x;
    if (e < E) atomicAdd(&counts[ei[E + e]], 1);
}

__global__ __launch_bounds__(256) void scan_kernel(
    const int* __restrict__ counts, int* __restrict__ row_ptr,
    int* __restrict__ cursor, int n)
{
    __shared__ int sums[256];
    const int t = threadIdx.x;
    const int chunk = (n + 255) / 256;
    const int beg = t * chunk;
    const int end = min(beg + chunk, n);
    int s = 0;
    for (int i = beg; i < end; ++i) s += counts[i];
    sums[t] = s;
    __syncthreads();
    for (int off = 1; off < 256; off <<= 1) {
        int v = (t >= off) ? sums[t - off] : 0;
        __syncthreads();
        sums[t] += v;
        __syncthreads();
    }
    int run = (t == 0) ? 0 : sums[t - 1];
    for (int i = beg; i < end; ++i) {
        row_ptr[i] = run;
        cursor[i]  = run;
        run += counts[i];
    }
    if (t == 0) row_ptr[n] = sums[255];
}

__global__ __launch_bounds__(256) void fill_kernel(
    const int* __restrict__ ei, const float* __restrict__ ew,
    int* __restrict__ cursor,
    int* __restrict__ src_sorted, float* __restrict__ w_sorted, int E)
{
    int e = blockIdx.x * 256 + threadIdx.x;
    if (e >= E) return;
    int d = ei[E + e];
    int p = atomicAdd(&cursor[d], 1);
    src_sorted[p] = ei[e];
    w_sorted[p]   = ew[e];
}

// ---- conversions ----------------------------------------------------------
__global__ __launch_bounds__(256) void to_bf16_vec(
    const float* __restrict__ in, __hip_bfloat16* __restrict__ out, int n4)
{
    int i = blockIdx.x * 256 + threadIdx.x;
    if (i >= n4) return;
    float4 v = *(const float4*)&in[i * 4];
    __hip_bfloat16 o[4] = { __float2bfloat16(v.x), __float2bfloat16(v.y),
                            __float2bfloat16(v.z), __float2bfloat16(v.w) };
    *(ushort4*)&out[i * 4] = *(ushort4*)o;
}

// out[c*K + k] = bf16(in[k*C + c])   (in: [K,C] fp32 row-major)
__global__ __launch_bounds__(256) void transpose_to_bf16(
    const float* __restrict__ in, __hip_bfloat16* __restrict__ out, int K, int C)
{
    int idx = blockIdx.x * 256 + threadIdx.x;
    if (idx >= K * C) return;
    int k = idx / C, c = idx % C;
    out[(size_t)c * K + k] = __float2bfloat16(in[idx]);
}

// w_lin [512,40] -> out[2][64][256]: out[seg][c][k] = w_lin[seg*256+k][c], 0 pad
__global__ __launch_bounds__(256) void transpose_wlin(
    const float* __restrict__ w, __hip_bfloat16* __restrict__ out)
{
    int idx = blockIdx.x * 256 + threadIdx.x;
    if (idx >= 2 * 64 * 256) return;
    int seg = idx >> 14;
    int c   = (idx >> 8) & 63;
    int k   = idx & 255;
    float v = (c < 40) ? w[(size_t)(seg * 256 + k) * 40 + c] : 0.f;
    out[idx] = __float2bfloat16(v);
}

// ---- gather: agg[v,:] = sum_e w_e * feat[src_e,:]  (bf16 in/out, fp32 acc) -
template <int C>
__global__ __launch_bounds__(256) void gather_bf16(
    const __hip_bfloat16* __restrict__ feat,
    const int*   __restrict__ srcs,
    const float* __restrict__ ws,
    const int*   __restrict__ rp,
    __hip_bfloat16* __restrict__ agg, int n)
{
    const int node = (blockIdx.x * 256 + threadIdx.x) >> 6;
    const int lane = threadIdx.x & 63;
    if (node >= n) return;
    const int beg = rp[node];
    const int end = rp[node + 1];
    constexpr int V = C / 64;
    float acc[V] = {};
    const unsigned short* fb = (const unsigned short*)feat;
    for (int e = beg; e < end; ++e) {
        int   s  = srcs[e];
        float wt = ws[e];
        const unsigned short* fp = fb + (size_t)s * C + lane * V;
        if constexpr (V == 2) {
            ushort2 u = *(const ushort2*)fp;
            acc[0] = fmaf(bf2f(u.x), wt, acc[0]);
            acc[1] = fmaf(bf2f(u.y), wt, acc[1]);
        } else {
            ushort4 u = *(const ushort4*)fp;
            acc[0] = fmaf(bf2f(u.x), wt, acc[0]);
            acc[1] = fmaf(bf2f(u.y), wt, acc[1]);
            acc[2] = fmaf(bf2f(u.z), wt, acc[2]);
            acc[3] = fmaf(bf2f(u.w), wt, acc[3]);
        }
    }
    __hip_bfloat16 o[V];
#pragma unroll
    for (int i = 0; i < V; ++i) o[i] = __float2bfloat16(acc[i]);
    if constexpr (V == 2)
        *(ushort2*)(agg + (size_t)node * C + lane * V) = *(ushort2*)o;
    else
        *(ushort4*)(agg + (size_t)node * C + lane * V) = *(ushort4*)o;
}

// ---- MFMA GEMM: C = relu(A0@W0 + A1@W1 + bias), NC=256, bf16 in/out -------
// A: [n,K] bf16 row-major.  WT: [256,K] bf16 (orig W transposed).
// 128x128 tile, BK=64, 4 waves (2x2 of 64x64), global_load_lds + XOR swizzle.
__global__ __launch_bounds__(256) void gemm_mfma(
    const __hip_bfloat16* __restrict__ A0, const __hip_bfloat16* __restrict__ A1,
    const __hip_bfloat16* __restrict__ W0T, const __hip_bfloat16* __restrict__ W1T,
    const float* __restrict__ bias,
    __hip_bfloat16* __restrict__ Cmat,
    int n, int K0, int K1)
{
    __shared__ __hip_bfloat16 Asl[128 * 64];   // 16 KB
    __shared__ __hip_bfloat16 Bsl[128 * 64];   // 16 KB
    const int bm = blockIdx.x >> 1;
    const int bn = blockIdx.x & 1;
    const int row0 = bm * 128, col0 = bn * 128;
    const int t = threadIdx.x, lane = t & 63, wid = t >> 6;
    const int wr = wid >> 1, wc = wid & 1;

    f32x4 acc[4][4] = {};

    for (int seg = 0; seg < 2; ++seg) {
        const __hip_bfloat16* A  = seg ? A1 : A0;
        const __hip_bfloat16* WT = seg ? W1T : W0T;
        const int K = seg ? K1 : K0;
        for (int k0 = 0; k0 < K; k0 += 64) {
#pragma unroll
            for (int i = 0; i < 4; ++i) {
                int idx = i * 256 + t;
                int r = idx >> 3, c = idx & 7;
                int gr = row0 + r; if (gr >= n) gr = n - 1;
                const __hip_bfloat16* srcA =
                    A + (size_t)gr * K + k0 + ((c ^ (r & 7)) << 3);
                __builtin_amdgcn_global_load_lds(
                    (const __attribute__((address_space(1))) void*)srcA,
                    (__attribute__((address_space(3))) void*)&Asl[idx * 8], 16, 0, 0);
                const __hip_bfloat16* srcB =
                    WT + (size_t)(col0 + r) * K + k0 + ((c ^ (r & 7)) << 3);
                __builtin_amdgcn_global_load_lds(
                    (const __attribute__((address_space(1))) void*)srcB,
                    (__attribute__((address_space(3))) void*)&Bsl[idx * 8], 16, 0, 0);
            }
            __syncthreads();
#pragma unroll
            for (int kh = 0; kh < 2; ++kh) {
                const int cchunk = kh * 4 + (lane >> 4);
                short8 af[4], bfr[4];
#pragma unroll
                for (int m = 0; m < 4; ++m) {
                    int r = wr * 64 + m * 16 + (lane & 15);
                    af[m] = *(const short8*)&Asl[r * 64 + ((cchunk ^ (r & 7)) << 3)];
                }
#pragma unroll
                for (int nn = 0; nn < 4; ++nn) {
                    int r = wc * 64 + nn * 16 + (lane & 15);
                    bfr[nn] = *(const short8*)&Bsl[r * 64 + ((cchunk ^ (r & 7)) << 3)];
                }
#pragma unroll
                for (int m = 0; m < 4; ++m)
#pragma unroll
                    for (int nn = 0; nn < 4; ++nn)
                        acc[m][nn] = __builtin_amdgcn_mfma_f32_16x16x32_bf16(
                            af[m], bfr[nn], acc[m][nn], 0, 0, 0);
            }
            __syncthreads();
        }
    }

#pragma unroll
    for (int nn = 0; nn < 4; ++nn) {
        int col = col0 + wc * 64 + nn * 16 + (lane & 15);
        float b = bias[col];
#pragma unroll
        for (int m = 0; m < 4; ++m) {
#pragma unroll
            for (int rg = 0; rg < 4; ++rg) {
                int row = row0 + wr * 64 + m * 16 + ((lane >> 4) * 4) + rg;
                if (row < n) {
                    float v = fmaxf(acc[m][nn][rg] + b, 0.f);
                    Cmat[(size_t)row * 256 + col] = __float2bfloat16(v);
                }
            }
        }
    }
}

// ---- head: out = log_softmax([x1|x2] @ w_lin + b_lin), MFMA + fused SM ----
// Tile 128 rows x 64 cols; 4 waves, each 32 rows (2 m-frags) x 4 n-frags.
__global__ __launch_bounds__(256) void head_mfma(
    const __hip_bfloat16* __restrict__ X1, const __hip_bfloat16* __restrict__ X2,
    const __hip_bfloat16* __restrict__ WLT,   // [2][64][256]
    const float* __restrict__ b_lin,
    float* __restrict__ out, int n)
{
    __shared__ __hip_bfloat16 Asl[128 * 64];  // 16 KB
    __shared__ __hip_bfloat16 Bsl[64 * 64];   // 8 KB
    const int row0 = blockIdx.x * 128;
    const int t = threadIdx.x, lane = t & 63, wid = t >> 6;

    f32x4 acc[2][4] = {};

    for (int seg = 0; seg < 2; ++seg) {
        const __hip_bfloat16* A  = seg ? X2 : X1;
        const __hip_bfloat16* WT = WLT + seg * 64 * 256;
        for (int k0 = 0; k0 < 256; k0 += 64) {
#pragma unroll
            for (int i = 0; i < 4; ++i) {
                int idx = i * 256 + t;
                int r = idx >> 3, c = idx & 7;
                int gr = row0 + r; if (gr >= n) gr = n - 1;
                const __hip_bfloat16* srcA =
                    A + (size_t)gr * 256 + k0 + ((c ^ (r & 7)) << 3);
                __builtin_amdgcn_global_load_lds(
                    (const __attribute__((address_space(1))) void*)srcA,
                    (__attribute__((address_space(3))) void*)&Asl[idx * 8], 16, 0, 0);
            }
#pragma unroll
            for (int i = 0; i < 2; ++i) {
                int idx = i * 256 + t;
                int r = idx >> 3, c = idx & 7;
                const __hip_bfloat16* srcB =
                    WT + (size_t)r * 256 + k0 + ((c ^ (r & 7)) << 3);
                __builtin_amdgcn_global_load_lds(
                    (const __attribute__((address_space(1))) void*)srcB,
                    (__attribute__((address_space(3))) void*)&Bsl[idx * 8], 16, 0, 0);
            }
            __syncthreads();
#pragma unroll
            for (int kh = 0; kh < 2; ++kh) {
                const int cchunk = kh * 4 + (lane >> 4);
                short8 af[2], bfr[4];
#pragma unroll
                for (int m = 0; m < 2; ++m) {
                    int r = wid * 32 + m * 16 + (lane & 15);
                    af[m] = *(const short8*)&Asl[r * 64 + ((cchunk ^ (r & 7)) << 3)];
                }
#pragma unroll
                for (int nn = 0; nn < 4; ++nn) {
                    int r = nn * 16 + (lane & 15);
                    bfr[nn] = *(const short8*)&Bsl[r * 64 + ((cchunk ^ (r & 7)) << 3)];
                }
#pragma unroll
                for (int m = 0; m < 2; ++m)
#pragma unroll
                    for (int nn = 0; nn < 4; ++nn)
                        acc[m][nn] = __builtin_amdgcn_mfma_f32_16x16x32_bf16(
                            af[m], bfr[nn], acc[m][nn], 0, 0, 0);
            }
            __syncthreads();
        }
    }

    // fused bias + log_softmax epilogue
    const int cl = lane & 15;
    float bb[4];
#pragma unroll
    for (int nn = 0; nn < 4; ++nn) {
        int col = nn * 16 + cl;
        bb[nn] = (col < 40) ? b_lin[col] : 0.f;
    }
#pragma unroll
    for (int m = 0; m < 2; ++m) {
#pragma unroll
        for (int rg = 0; rg < 4; ++rg) {
            float v[4];
            float mx = -1e30f;
#pragma unroll
            for (int nn = 0; nn < 4; ++nn) {
                int col = nn * 16 + cl;
                v[nn] = acc[m][nn][rg] + bb[nn];
                if (col < 40) mx = fmaxf(mx, v[nn]);
            }
#pragma unroll
            for (int off = 1; off < 16; off <<= 1)
                mx = fmaxf(mx, __shfl_xor(mx, off, 64));
            float s = 0.f;
#pragma unroll
            for (int nn = 0; nn < 4; ++nn) {
                int col = nn * 16 + cl;
                if (col < 40) s += expf(v[nn] - mx);
            }
#pragma unroll
            for (int off = 1; off < 16; off <<= 1)
                s += __shfl_xor(s, off, 64);
            float ls = logf(s);
            int row = row0 + wid * 32 + m * 16 + ((lane >> 4) * 4) + rg;
            if (row < n) {
#pragma unroll
                for (int nn = 0; nn < 4; ++nn) {
                    int col = nn * 16 + cl;
                    if (col < 40)
                        out[(size_t)row * 40 + col] = v[nn] - mx - ls;
                }
            }
        }
    }
}

// ---------------------------------------------------------------------------
extern "C" void kernel_launch(void* const* d_in, const int* in_sizes, int n_in,
                              void* d_out, int out_size, void* d_ws, size_t ws_size,
                              hipStream_t stream)
{
    const float* x       = (const float*)d_in[0];
    const int*   ei      = (const int*)  d_in[1];
    const float* ew      = (const float*)d_in[2];
    const float* w1_rel  = (const float*)d_in[3];
    const float* b1      = (const float*)d_in[4];
    const float* w1_root = (const float*)d_in[5];
    const float* w2_rel  = (const float*)d_in[6];
    const float* b2      = (const float*)d_in[7];
    const float* w2_root = (const float*)d_in[8];
    const float* w_lin   = (const float*)d_in[9];
    const float* b_lin   = (const float*)d_in[10];
    float* out = (float*)d_out;

    const int N = in_sizes[0] / 128;   // 50000
    const int E = in_sizes[2];         // 800000

    auto align = [](char*& p, size_t bytes) {
        char* r = p;
        p += (bytes + 255) & ~(size_t)255;
        return r;
    };
    char* wp = (char*)d_ws;
    __hip_bfloat16* xb     = (__hip_bfloat16*)align(wp, (size_t)N * 128 * 2);
    __hip_bfloat16* agg1b  = (__hip_bfloat16*)align(wp, (size_t)N * 128 * 2);
    __hip_bfloat16* x1b    = (__hip_bfloat16*)align(wp, (size_t)N * 256 * 2);
    __hip_bfloat16* agg2b  = (__hip_bfloat16*)align(wp, (size_t)N * 256 * 2);
    __hip_bfloat16* x2b    = (__hip_bfloat16*)align(wp, (size_t)N * 256 * 2);
    __hip_bfloat16* w1relT  = (__hip_bfloat16*)align(wp, 256 * 128 * 2);
    __hip_bfloat16* w1rootT = (__hip_bfloat16*)align(wp, 256 * 128 * 2);
    __hip_bfloat16* w2relT  = (__hip_bfloat16*)align(wp, 256 * 256 * 2);
    __hip_bfloat16* w2rootT = (__hip_bfloat16*)align(wp, 256 * 256 * 2);
    __hip_bfloat16* wlinT   = (__hip_bfloat16*)align(wp, 2 * 64 * 256 * 2);
    int*   counts     = (int*)align(wp, (size_t)N * 4);
    int*   row_ptr    = (int*)align(wp, (size_t)(N + 1) * 4);
    int*   cursor     = (int*)align(wp, (size_t)N * 4);
    int*   src_sorted = (int*)align(wp, (size_t)E * 4);
    float* w_sorted   = (float*)align(wp, (size_t)E * 4);

    const int eb = (E + 255) / 256;

    // CSR build
    hipMemsetAsync(counts, 0, (size_t)N * 4, stream);
    count_kernel<<<eb, 256, 0, stream>>>(ei, counts, E);
    scan_kernel<<<1, 256, 0, stream>>>(counts, row_ptr, cursor, N);
    fill_kernel<<<eb, 256, 0, stream>>>(ei, ew, cursor, src_sorted, w_sorted, E);

    // conversions
    {
        int n4 = N * 128 / 4;
        to_bf16_vec<<<(n4 + 255) / 256, 256, 0, stream>>>(x, xb, n4);
        transpose_to_bf16<<<(128 * 256 + 255) / 256, 256, 0, stream>>>(w1_rel,  w1relT, 128, 256);
        transpose_to_bf16<<<(128 * 256 + 255) / 256, 256, 0, stream>>>(w1_root, w1rootT, 128, 256);
        transpose_to_bf16<<<(256 * 256 + 255) / 256, 256, 0, stream>>>(w2_rel,  w2relT, 256, 256);
        transpose_to_bf16<<<(256 * 256 + 255) / 256, 256, 0, stream>>>(w2_root, w2rootT, 256, 256);
        transpose_wlin<<<(2 * 64 * 256 + 255) / 256, 256, 0, stream>>>(w_lin, wlinT);
    }

    const int gather_blocks = (N * 64 + 255) / 256;
    const int gemm_grid     = ((N + 127) / 128) * 2;
    const int head_grid     = (N + 127) / 128;

    // layer 1
    gather_bf16<128><<<gather_blocks, 256, 0, stream>>>(
        xb, src_sorted, w_sorted, row_ptr, agg1b, N);
    gemm_mfma<<<gemm_grid, 256, 0, stream>>>(
        agg1b, xb, w1relT, w1rootT, b1, x1b, N, 128, 128);
    // layer 2
    gather_bf16<256><<<gather_blocks, 256, 0, stream>>>(
        x1b, src_sorted, w_sorted, row_ptr, agg2b, N);
    gemm_mfma<<<gemm_grid, 256, 0, stream>>>(
        agg2b, x1b, w2relT, w2rootT, b2, x2b, N, 256, 256);
    // head
    head_mfma<<<head_grid, 256, 0, stream>>>(x1b, x2b, wlinT, b_lin, out, N);
}

// Round 4
// 288.162 us; speedup vs baseline: 15.6542x; 1.6954x over previous
//
#include <hip/hip_runtime.h>
#include <hip/hip_bf16.h>
#include <math.h>

// ---------------------------------------------------------------------------
// GraphConv GNN, round 3: parallel CSR scan + MLP-unrolled gathers.
// Pipeline: count -> 3-phase scan -> fill(int2) -> conv -> gather1 -> gemm1
//           -> gather2 -> gemm2 -> head(MFMA, fused log-softmax).
// ---------------------------------------------------------------------------

typedef __attribute__((ext_vector_type(8))) short short8;
typedef __attribute__((ext_vector_type(4))) float f32x4;

static __device__ __forceinline__ float bf2f(unsigned short u) {
    return __uint_as_float(((unsigned)u) << 16);
}

// ---- CSR build ------------------------------------------------------------
__global__ __launch_bounds__(256) void count_kernel(
    const int* __restrict__ ei, int* __restrict__ counts, int E)
{
    int e = blockIdx.x * 256 + threadIdx.x;
    if (e < E) atomicAdd(&counts[ei[E + e]], 1);
}

// phase 1: per-block (256-elem) sums
__global__ __launch_bounds__(256) void scan_block_sums(
    const int* __restrict__ counts, int* __restrict__ bsum, int n)
{
    __shared__ int sh[256];
    int idx = blockIdx.x * 256 + threadIdx.x;
    sh[threadIdx.x] = (idx < n) ? counts[idx] : 0;
    __syncthreads();
#pragma unroll
    for (int off = 128; off; off >>= 1) {
        if (threadIdx.x < off) sh[threadIdx.x] += sh[threadIdx.x + off];
        __syncthreads();
    }
    if (threadIdx.x == 0) bsum[blockIdx.x] = sh[0];
}

// phase 2: single block scans the (<=256) block sums -> exclusive prefixes
__global__ __launch_bounds__(256) void scan_bsum(
    const int* __restrict__ bsum, int* __restrict__ bpre, int nb)
{
    __shared__ int sh[256];
    int t = threadIdx.x;
    int v = (t < nb) ? bsum[t] : 0;
    sh[t] = v;
    __syncthreads();
#pragma unroll
    for (int off = 1; off < 256; off <<= 1) {
        int u = (t >= off) ? sh[t - off] : 0;
        __syncthreads();
        sh[t] += u;
        __syncthreads();
    }
    bpre[t] = sh[t] - v;   // exclusive
}

// phase 3: per-block Hillis-Steele + block offset -> row_ptr & cursor
__global__ __launch_bounds__(256) void scan_final(
    const int* __restrict__ counts, const int* __restrict__ bpre,
    int* __restrict__ row_ptr, int* __restrict__ cursor, int n, int Etot)
{
    __shared__ int sh[256];
    int t = threadIdx.x;
    int idx = blockIdx.x * 256 + t;
    int v = (idx < n) ? counts[idx] : 0;
    sh[t] = v;
    __syncthreads();
#pragma unroll
    for (int off = 1; off < 256; off <<= 1) {
        int u = (t >= off) ? sh[t - off] : 0;
        __syncthreads();
        sh[t] += u;
        __syncthreads();
    }
    if (idx < n) {
        int val = bpre[blockIdx.x] + sh[t] - v;
        row_ptr[idx] = val;
        cursor[idx]  = val;
    }
    if (idx == 0) row_ptr[n] = Etot;
}

__global__ __launch_bounds__(256) void fill_kernel(
    const int* __restrict__ ei, const float* __restrict__ ew,
    int* __restrict__ cursor, int2* __restrict__ edges, int E)
{
    int e = blockIdx.x * 256 + threadIdx.x;
    if (e >= E) return;
    int d = ei[E + e];
    int p = atomicAdd(&cursor[d], 1);
    edges[p] = make_int2(ei[e], __float_as_int(ew[e]));
}

// ---- conversions ----------------------------------------------------------
__global__ __launch_bounds__(256) void to_bf16_vec(
    const float* __restrict__ in, __hip_bfloat16* __restrict__ out, int n4)
{
    int i = blockIdx.x * 256 + threadIdx.x;
    if (i >= n4) return;
    float4 v = *(const float4*)&in[i * 4];
    __hip_bfloat16 o[4] = { __float2bfloat16(v.x), __float2bfloat16(v.y),
                            __float2bfloat16(v.z), __float2bfloat16(v.w) };
    *(ushort4*)&out[i * 4] = *(ushort4*)o;
}

// all weight transposes in one launch (229376 threads)
__global__ __launch_bounds__(256) void prep_weights(
    const float* __restrict__ w1_rel, const float* __restrict__ w1_root,
    const float* __restrict__ w2_rel, const float* __restrict__ w2_root,
    const float* __restrict__ w_lin,
    __hip_bfloat16* __restrict__ w1relT, __hip_bfloat16* __restrict__ w1rootT,
    __hip_bfloat16* __restrict__ w2relT, __hip_bfloat16* __restrict__ w2rootT,
    __hip_bfloat16* __restrict__ wlinT)
{
    int idx = blockIdx.x * 256 + threadIdx.x;
    if (idx < 65536) {                       // w1_rel/w1_root [128,256] -> [256,128]
        const float* src = (idx < 32768) ? w1_rel : w1_root;
        __hip_bfloat16* dst = (idx < 32768) ? w1relT : w1rootT;
        int i = idx & 32767;
        int k = i >> 8, c = i & 255;
        dst[c * 128 + k] = __float2bfloat16(src[i]);
    } else if (idx < 196608) {               // w2_rel/w2_root [256,256] -> [256,256]^T
        int j = idx - 65536;
        const float* src = (j < 65536) ? w2_rel : w2_root;
        __hip_bfloat16* dst = (j < 65536) ? w2relT : w2rootT;
        int i = j & 65535;
        int k = i >> 8, c = i & 255;
        dst[c * 256 + k] = __float2bfloat16(src[i]);
    } else if (idx < 229376) {               // w_lin [512,40] -> [2][64][256], pad
        int i = idx - 196608;
        int seg = i >> 14, c = (i >> 8) & 63, k = i & 255;
        float v = (c < 40) ? w_lin[(size_t)(seg * 256 + k) * 40 + c] : 0.f;
        wlinT[i] = __float2bfloat16(v);
    }
}

// ---- gather: agg[v,:] = sum_e w_e * feat[src_e,:]  (bf16, fp32 acc) -------
// one wave per node; 4-edge unroll for memory-level parallelism.
template <int C>
__global__ __launch_bounds__(256) void gather_bf16(
    const __hip_bfloat16* __restrict__ feat,
    const int2* __restrict__ edges,
    const int*  __restrict__ rp,
    __hip_bfloat16* __restrict__ agg, int n)
{
    const int node = (blockIdx.x * 256 + threadIdx.x) >> 6;
    const int lane = threadIdx.x & 63;
    if (node >= n) return;
    int e   = rp[node];
    const int end = rp[node + 1];
    constexpr int V = C / 64;
    float acc[V] = {};
    const unsigned short* fb = (const unsigned short*)feat;
    const unsigned loff = (unsigned)lane * V;

    for (; e + 4 <= end; e += 4) {
        int2 p0 = edges[e + 0], p1 = edges[e + 1];
        int2 p2 = edges[e + 2], p3 = edges[e + 3];
        float w0 = __int_as_float(p0.y), w1 = __int_as_float(p1.y);
        float w2 = __int_as_float(p2.y), w3 = __int_as_float(p3.y);
        if constexpr (V == 4) {
            ushort4 u0 = *(const ushort4*)(fb + (unsigned)p0.x * C + loff);
            ushort4 u1 = *(const ushort4*)(fb + (unsigned)p1.x * C + loff);
            ushort4 u2 = *(const ushort4*)(fb + (unsigned)p2.x * C + loff);
            ushort4 u3 = *(const ushort4*)(fb + (unsigned)p3.x * C + loff);
            acc[0] = fmaf(bf2f(u0.x), w0, fmaf(bf2f(u1.x), w1,
                     fmaf(bf2f(u2.x), w2, fmaf(bf2f(u3.x), w3, acc[0]))));
            acc[1] = fmaf(bf2f(u0.y), w0, fmaf(bf2f(u1.y), w1,
                     fmaf(bf2f(u2.y), w2, fmaf(bf2f(u3.y), w3, acc[1]))));
            acc[2] = fmaf(bf2f(u0.z), w0, fmaf(bf2f(u1.z), w1,
                     fmaf(bf2f(u2.z), w2, fmaf(bf2f(u3.z), w3, acc[2]))));
            acc[3] = fmaf(bf2f(u0.w), w0, fmaf(bf2f(u1.w), w1,
                     fmaf(bf2f(u2.w), w2, fmaf(bf2f(u3.w), w3, acc[3]))));
        } else {
            ushort2 u0 = *(const ushort2*)(fb + (unsigned)p0.x * C + loff);
            ushort2 u1 = *(const ushort2*)(fb + (unsigned)p1.x * C + loff);
            ushort2 u2 = *(const ushort2*)(fb + (unsigned)p2.x * C + loff);
            ushort2 u3 = *(const ushort2*)(fb + (unsigned)p3.x * C + loff);
            acc[0] = fmaf(bf2f(u0.x), w0, fmaf(bf2f(u1.x), w1,
                     fmaf(bf2f(u2.x), w2, fmaf(bf2f(u3.x), w3, acc[0]))));
            acc[1] = fmaf(bf2f(u0.y), w0, fmaf(bf2f(u1.y), w1,
                     fmaf(bf2f(u2.y), w2, fmaf(bf2f(u3.y), w3, acc[1]))));
        }
    }
    for (; e < end; ++e) {
        int2 p = edges[e];
        float wt = __int_as_float(p.y);
        const unsigned short* fp = fb + (unsigned)p.x * C + loff;
        if constexpr (V == 4) {
            ushort4 u = *(const ushort4*)fp;
            acc[0] = fmaf(bf2f(u.x), wt, acc[0]);
            acc[1] = fmaf(bf2f(u.y), wt, acc[1]);
            acc[2] = fmaf(bf2f(u.z), wt, acc[2]);
            acc[3] = fmaf(bf2f(u.w), wt, acc[3]);
        } else {
            ushort2 u = *(const ushort2*)fp;
            acc[0] = fmaf(bf2f(u.x), wt, acc[0]);
            acc[1] = fmaf(bf2f(u.y), wt, acc[1]);
        }
    }
    __hip_bfloat16 o[V];
#pragma unroll
    for (int i = 0; i < V; ++i) o[i] = __float2bfloat16(acc[i]);
    if constexpr (V == 2)
        *(ushort2*)(agg + (size_t)node * C + loff) = *(ushort2*)o;
    else
        *(ushort4*)(agg + (size_t)node * C + loff) = *(ushort4*)o;
}

// ---- MFMA GEMM: C = relu(A0@W0 + A1@W1 + bias), NC=256, bf16 in/out -------
__global__ __launch_bounds__(256) void gemm_mfma(
    const __hip_bfloat16* __restrict__ A0, const __hip_bfloat16* __restrict__ A1,
    const __hip_bfloat16* __restrict__ W0T, const __hip_bfloat16* __restrict__ W1T,
    const float* __restrict__ bias,
    __hip_bfloat16* __restrict__ Cmat,
    int n, int K0, int K1)
{
    __shared__ __hip_bfloat16 Asl[128 * 64];
    __shared__ __hip_bfloat16 Bsl[128 * 64];
    const int bm = blockIdx.x >> 1;
    const int bn = blockIdx.x & 1;
    const int row0 = bm * 128, col0 = bn * 128;
    const int t = threadIdx.x, lane = t & 63, wid = t >> 6;
    const int wr = wid >> 1, wc = wid & 1;

    f32x4 acc[4][4] = {};

    for (int seg = 0; seg < 2; ++seg) {
        const __hip_bfloat16* A  = seg ? A1 : A0;
        const __hip_bfloat16* WT = seg ? W1T : W0T;
        const int K = seg ? K1 : K0;
        for (int k0 = 0; k0 < K; k0 += 64) {
#pragma unroll
            for (int i = 0; i < 4; ++i) {
                int idx = i * 256 + t;
                int r = idx >> 3, c = idx & 7;
                int gr = row0 + r; if (gr >= n) gr = n - 1;
                const __hip_bfloat16* srcA =
                    A + (size_t)gr * K + k0 + ((c ^ (r & 7)) << 3);
                __builtin_amdgcn_global_load_lds(
                    (const __attribute__((address_space(1))) void*)srcA,
                    (__attribute__((address_space(3))) void*)&Asl[idx * 8], 16, 0, 0);
                const __hip_bfloat16* srcB =
                    WT + (size_t)(col0 + r) * K + k0 + ((c ^ (r & 7)) << 3);
                __builtin_amdgcn_global_load_lds(
                    (const __attribute__((address_space(1))) void*)srcB,
                    (__attribute__((address_space(3))) void*)&Bsl[idx * 8], 16, 0, 0);
            }
            __syncthreads();
#pragma unroll
            for (int kh = 0; kh < 2; ++kh) {
                const int cchunk = kh * 4 + (lane >> 4);
                short8 af[4], bfr[4];
#pragma unroll
                for (int m = 0; m < 4; ++m) {
                    int r = wr * 64 + m * 16 + (lane & 15);
                    af[m] = *(const short8*)&Asl[r * 64 + ((cchunk ^ (r & 7)) << 3)];
                }
#pragma unroll
                for (int nn = 0; nn < 4; ++nn) {
                    int r = wc * 64 + nn * 16 + (lane & 15);
                    bfr[nn] = *(const short8*)&Bsl[r * 64 + ((cchunk ^ (r & 7)) << 3)];
                }
#pragma unroll
                for (int m = 0; m < 4; ++m)
#pragma unroll
                    for (int nn = 0; nn < 4; ++nn)
                        acc[m][nn] = __builtin_amdgcn_mfma_f32_16x16x32_bf16(
                            af[m], bfr[nn], acc[m][nn], 0, 0, 0);
            }
            __syncthreads();
        }
    }

#pragma unroll
    for (int nn = 0; nn < 4; ++nn) {
        int col = col0 + wc * 64 + nn * 16 + (lane & 15);
        float b = bias[col];
#pragma unroll
        for (int m = 0; m < 4; ++m) {
#pragma unroll
            for (int rg = 0; rg < 4; ++rg) {
                int row = row0 + wr * 64 + m * 16 + ((lane >> 4) * 4) + rg;
                if (row < n) {
                    float v = fmaxf(acc[m][nn][rg] + b, 0.f);
                    Cmat[(size_t)row * 256 + col] = __float2bfloat16(v);
                }
            }
        }
    }
}

// ---- head: out = log_softmax([x1|x2] @ w_lin + b_lin), MFMA fused ---------
__global__ __launch_bounds__(256) void head_mfma(
    const __hip_bfloat16* __restrict__ X1, const __hip_bfloat16* __restrict__ X2,
    const __hip_bfloat16* __restrict__ WLT,   // [2][64][256]
    const float* __restrict__ b_lin,
    float* __restrict__ out, int n)
{
    __shared__ __hip_bfloat16 Asl[128 * 64];
    __shared__ __hip_bfloat16 Bsl[64 * 64];
    const int row0 = blockIdx.x * 128;
    const int t = threadIdx.x, lane = t & 63, wid = t >> 6;

    f32x4 acc[2][4] = {};

    for (int seg = 0; seg < 2; ++seg) {
        const __hip_bfloat16* A  = seg ? X2 : X1;
        const __hip_bfloat16* WT = WLT + seg * 64 * 256;
        for (int k0 = 0; k0 < 256; k0 += 64) {
#pragma unroll
            for (int i = 0; i < 4; ++i) {
                int idx = i * 256 + t;
                int r = idx >> 3, c = idx & 7;
                int gr = row0 + r; if (gr >= n) gr = n - 1;
                const __hip_bfloat16* srcA =
                    A + (size_t)gr * 256 + k0 + ((c ^ (r & 7)) << 3);
                __builtin_amdgcn_global_load_lds(
                    (const __attribute__((address_space(1))) void*)srcA,
                    (__attribute__((address_space(3))) void*)&Asl[idx * 8], 16, 0, 0);
            }
#pragma unroll
            for (int i = 0; i < 2; ++i) {
                int idx = i * 256 + t;
                int r = idx >> 3, c = idx & 7;
                const __hip_bfloat16* srcB =
                    WT + (size_t)r * 256 + k0 + ((c ^ (r & 7)) << 3);
                __builtin_amdgcn_global_load_lds(
                    (const __attribute__((address_space(1))) void*)srcB,
                    (__attribute__((address_space(3))) void*)&Bsl[idx * 8], 16, 0, 0);
            }
            __syncthreads();
#pragma unroll
            for (int kh = 0; kh < 2; ++kh) {
                const int cchunk = kh * 4 + (lane >> 4);
                short8 af[2], bfr[4];
#pragma unroll
                for (int m = 0; m < 2; ++m) {
                    int r = wid * 32 + m * 16 + (lane & 15);
                    af[m] = *(const short8*)&Asl[r * 64 + ((cchunk ^ (r & 7)) << 3)];
                }
#pragma unroll
                for (int nn = 0; nn < 4; ++nn) {
                    int r = nn * 16 + (lane & 15);
                    bfr[nn] = *(const short8*)&Bsl[r * 64 + ((cchunk ^ (r & 7)) << 3)];
                }
#pragma unroll
                for (int m = 0; m < 2; ++m)
#pragma unroll
                    for (int nn = 0; nn < 4; ++nn)
                        acc[m][nn] = __builtin_amdgcn_mfma_f32_16x16x32_bf16(
                            af[m], bfr[nn], acc[m][nn], 0, 0, 0);
            }
            __syncthreads();
        }
    }

    const int cl = lane & 15;
    float bb[4];
#pragma unroll
    for (int nn = 0; nn < 4; ++nn) {
        int col = nn * 16 + cl;
        bb[nn] = (col < 40) ? b_lin[col] : 0.f;
    }
#pragma unroll
    for (int m = 0; m < 2; ++m) {
#pragma unroll
        for (int rg = 0; rg < 4; ++rg) {
            float v[4];
            float mx = -1e30f;
#pragma unroll
            for (int nn = 0; nn < 4; ++nn) {
                int col = nn * 16 + cl;
                v[nn] = acc[m][nn][rg] + bb[nn];
                if (col < 40) mx = fmaxf(mx, v[nn]);
            }
#pragma unroll
            for (int off = 1; off < 16; off <<= 1)
                mx = fmaxf(mx, __shfl_xor(mx, off, 64));
            float s = 0.f;
#pragma unroll
            for (int nn = 0; nn < 4; ++nn) {
                int col = nn * 16 + cl;
                if (col < 40) s += expf(v[nn] - mx);
            }
#pragma unroll
            for (int off = 1; off < 16; off <<= 1)
                s += __shfl_xor(s, off, 64);
            float ls = logf(s);
            int row = row0 + wid * 32 + m * 16 + ((lane >> 4) * 4) + rg;
            if (row < n) {
#pragma unroll
                for (int nn = 0; nn < 4; ++nn) {
                    int col = nn * 16 + cl;
                    if (col < 40)
                        out[(size_t)row * 40 + col] = v[nn] - mx - ls;
                }
            }
        }
    }
}

// ---------------------------------------------------------------------------
extern "C" void kernel_launch(void* const* d_in, const int* in_sizes, int n_in,
                              void* d_out, int out_size, void* d_ws, size_t ws_size,
                              hipStream_t stream)
{
    const float* x       = (const float*)d_in[0];
    const int*   ei      = (const int*)  d_in[1];
    const float* ew      = (const float*)d_in[2];
    const float* w1_rel  = (const float*)d_in[3];
    const float* b1      = (const float*)d_in[4];
    const float* w1_root = (const float*)d_in[5];
    const float* w2_rel  = (const float*)d_in[6];
    const float* b2      = (const float*)d_in[7];
    const float* w2_root = (const float*)d_in[8];
    const float* w_lin   = (const float*)d_in[9];
    const float* b_lin   = (const float*)d_in[10];
    float* out = (float*)d_out;

    const int N = in_sizes[0] / 128;   // 50000
    const int E = in_sizes[2];         // 800000

    auto align = [](char*& p, size_t bytes) {
        char* r = p;
        p += (bytes + 255) & ~(size_t)255;
        return r;
    };
    char* wp = (char*)d_ws;
    __hip_bfloat16* xb     = (__hip_bfloat16*)align(wp, (size_t)N * 128 * 2);
    __hip_bfloat16* agg1b  = (__hip_bfloat16*)align(wp, (size_t)N * 128 * 2);
    __hip_bfloat16* x1b    = (__hip_bfloat16*)align(wp, (size_t)N * 256 * 2);
    __hip_bfloat16* agg2b  = (__hip_bfloat16*)align(wp, (size_t)N * 256 * 2);
    __hip_bfloat16* x2b    = (__hip_bfloat16*)align(wp, (size_t)N * 256 * 2);
    __hip_bfloat16* w1relT  = (__hip_bfloat16*)align(wp, 256 * 128 * 2);
    __hip_bfloat16* w1rootT = (__hip_bfloat16*)align(wp, 256 * 128 * 2);
    __hip_bfloat16* w2relT  = (__hip_bfloat16*)align(wp, 256 * 256 * 2);
    __hip_bfloat16* w2rootT = (__hip_bfloat16*)align(wp, 256 * 256 * 2);
    __hip_bfloat16* wlinT   = (__hip_bfloat16*)align(wp, 2 * 64 * 256 * 2);
    int*   counts  = (int*)align(wp, (size_t)N * 4);
    int*   row_ptr = (int*)align(wp, (size_t)(N + 1) * 4);
    int*   cursor  = (int*)align(wp, (size_t)N * 4);
    int*   bsum    = (int*)align(wp, 256 * 4);
    int*   bpre    = (int*)align(wp, 256 * 4);
    int2*  edges   = (int2*)align(wp, (size_t)E * 8);

    const int eb = (E + 255) / 256;
    const int nb = (N + 255) / 256;   // 196 <= 256

    // CSR build
    hipMemsetAsync(counts, 0, (size_t)N * 4, stream);
    count_kernel<<<eb, 256, 0, stream>>>(ei, counts, E);
    scan_block_sums<<<nb, 256, 0, stream>>>(counts, bsum, N);
    scan_bsum<<<1, 256, 0, stream>>>(bsum, bpre, nb);
    scan_final<<<nb, 256, 0, stream>>>(counts, bpre, row_ptr, cursor, N, E);
    fill_kernel<<<eb, 256, 0, stream>>>(ei, ew, cursor, edges, E);

    // conversions
    {
        int n4 = N * 128 / 4;
        to_bf16_vec<<<(n4 + 255) / 256, 256, 0, stream>>>(x, xb, n4);
        prep_weights<<<(229376 + 255) / 256, 256, 0, stream>>>(
            w1_rel, w1_root, w2_rel, w2_root, w_lin,
            w1relT, w1rootT, w2relT, w2rootT, wlinT);
    }

    const int gather_blocks = (N * 64 + 255) / 256;
    const int gemm_grid     = ((N + 127) / 128) * 2;
    const int head_grid     = (N + 127) / 128;

    // layer 1
    gather_bf16<128><<<gather_blocks, 256, 0, stream>>>(
        xb, edges, row_ptr, agg1b, N);
    gemm_mfma<<<gemm_grid, 256, 0, stream>>>(
        agg1b, xb, w1relT, w1rootT, b1, x1b, N, 128, 128);
    // layer 2
    gather_bf16<256><<<gather_blocks, 256, 0, stream>>>(
        x1b, edges, row_ptr, agg2b, N);
    gemm_mfma<<<gemm_grid, 256, 0, stream>>>(
        agg2b, x1b, w2relT, w2rootT, b2, x2b, N, 256, 256);
    // head
    head_mfma<<<head_grid, 256, 0, stream>>>(x1b, x2b, wlinT, b_lin, out, N);
}

// Round 5
// 269.173 us; speedup vs baseline: 16.7585x; 1.0705x over previous
//
#include <hip/hip_runtime.h>
#include <hip/hip_bf16.h>
#include <math.h>

// ---------------------------------------------------------------------------
// GraphConv GNN, round 4: 8-deep gather unroll + fused prep kernel.
// ---------------------------------------------------------------------------

typedef __attribute__((ext_vector_type(8))) short short8;
typedef __attribute__((ext_vector_type(4))) float f32x4;

static __device__ __forceinline__ float bf2f(unsigned short u) {
    return __uint_as_float(((unsigned)u) << 16);
}

// ---- CSR scan -------------------------------------------------------------
__global__ __launch_bounds__(256) void scan_block_sums(
    const int* __restrict__ counts, int* __restrict__ bsum, int n)
{
    __shared__ int sh[256];
    int idx = blockIdx.x * 256 + threadIdx.x;
    sh[threadIdx.x] = (idx < n) ? counts[idx] : 0;
    __syncthreads();
#pragma unroll
    for (int off = 128; off; off >>= 1) {
        if (threadIdx.x < off) sh[threadIdx.x] += sh[threadIdx.x + off];
        __syncthreads();
    }
    if (threadIdx.x == 0) bsum[blockIdx.x] = sh[0];
}

__global__ __launch_bounds__(256) void scan_bsum(
    const int* __restrict__ bsum, int* __restrict__ bpre, int nb)
{
    __shared__ int sh[256];
    int t = threadIdx.x;
    int v = (t < nb) ? bsum[t] : 0;
    sh[t] = v;
    __syncthreads();
#pragma unroll
    for (int off = 1; off < 256; off <<= 1) {
        int u = (t >= off) ? sh[t - off] : 0;
        __syncthreads();
        sh[t] += u;
        __syncthreads();
    }
    bpre[t] = sh[t] - v;   // exclusive
}

__global__ __launch_bounds__(256) void scan_final(
    const int* __restrict__ counts, const int* __restrict__ bpre,
    int* __restrict__ row_ptr, int* __restrict__ cursor, int n, int Etot)
{
    __shared__ int sh[256];
    int t = threadIdx.x;
    int idx = blockIdx.x * 256 + t;
    int v = (idx < n) ? counts[idx] : 0;
    sh[t] = v;
    __syncthreads();
#pragma unroll
    for (int off = 1; off < 256; off <<= 1) {
        int u = (t >= off) ? sh[t - off] : 0;
        __syncthreads();
        sh[t] += u;
        __syncthreads();
    }
    if (idx < n) {
        int val = bpre[blockIdx.x] + sh[t] - v;
        row_ptr[idx] = val;
        cursor[idx]  = val;
    }
    if (idx == 0) row_ptr[n] = Etot;
}

__global__ __launch_bounds__(256) void fill_kernel(
    const int* __restrict__ ei, const float* __restrict__ ew,
    int* __restrict__ cursor, int2* __restrict__ edges, int E)
{
    int e = blockIdx.x * 256 + threadIdx.x;
    if (e >= E) return;
    int d = ei[E + e];
    int p = atomicAdd(&cursor[d], 1);
    edges[p] = make_int2(ei[e], __float_as_int(ew[e]));
}

// ---- fused prep: count atomics + x->bf16 + weight transposes --------------
// idx ranges: [0,E) count; [E, E+NX8) x->bf16 (8-wide); then 229376 weights.
__global__ __launch_bounds__(256) void prep_all(
    const int* __restrict__ ei, int* __restrict__ counts, int E,
    const float* __restrict__ x, __hip_bfloat16* __restrict__ xb, int NX8,
    const float* __restrict__ w1_rel, const float* __restrict__ w1_root,
    const float* __restrict__ w2_rel, const float* __restrict__ w2_root,
    const float* __restrict__ w_lin,
    __hip_bfloat16* __restrict__ w1relT, __hip_bfloat16* __restrict__ w1rootT,
    __hip_bfloat16* __restrict__ w2relT, __hip_bfloat16* __restrict__ w2rootT,
    __hip_bfloat16* __restrict__ wlinT)
{
    int idx = blockIdx.x * 256 + threadIdx.x;
    if (idx < E) {
        atomicAdd(&counts[ei[E + idx]], 1);
        return;
    }
    idx -= E;
    if (idx < NX8) {   // x -> bf16, 8 elems/thread
        float4 a = *(const float4*)&x[(size_t)idx * 8];
        float4 b = *(const float4*)&x[(size_t)idx * 8 + 4];
        __hip_bfloat16 o[8] = {
            __float2bfloat16(a.x), __float2bfloat16(a.y),
            __float2bfloat16(a.z), __float2bfloat16(a.w),
            __float2bfloat16(b.x), __float2bfloat16(b.y),
            __float2bfloat16(b.z), __float2bfloat16(b.w) };
        *(short8*)&xb[(size_t)idx * 8] = *(short8*)o;
        return;
    }
    idx -= NX8;
    if (idx < 65536) {                       // w1_rel/w1_root [128,256] -> [256,128]
        const float* src = (idx < 32768) ? w1_rel : w1_root;
        __hip_bfloat16* dst = (idx < 32768) ? w1relT : w1rootT;
        int i = idx & 32767;
        int k = i >> 8, c = i & 255;
        dst[c * 128 + k] = __float2bfloat16(src[i]);
    } else if (idx < 196608) {               // w2_rel/w2_root [256,256]^T
        int j = idx - 65536;
        const float* src = (j < 65536) ? w2_rel : w2_root;
        __hip_bfloat16* dst = (j < 65536) ? w2relT : w2rootT;
        int i = j & 65535;
        int k = i >> 8, c = i & 255;
        dst[c * 256 + k] = __float2bfloat16(src[i]);
    } else if (idx < 229376) {               // w_lin [512,40] -> [2][64][256]
        int i = idx - 196608;
        int seg = i >> 14, c = (i >> 8) & 63, k = i & 255;
        float v = (c < 40) ? w_lin[(size_t)(seg * 256 + k) * 40 + c] : 0.f;
        wlinT[i] = __float2bfloat16(v);
    }
}

// ---- gather: agg[v,:] = sum_e w_e * feat[src_e,:]  (bf16, fp32 acc) -------
// one wave per node; 8-edge unroll for memory-level parallelism.
template <int C>
__global__ __launch_bounds__(256) void gather_bf16(
    const __hip_bfloat16* __restrict__ feat,
    const int2* __restrict__ edges,
    const int*  __restrict__ rp,
    __hip_bfloat16* __restrict__ agg, int n)
{
    const int node = (blockIdx.x * 256 + threadIdx.x) >> 6;
    const int lane = threadIdx.x & 63;
    if (node >= n) return;
    int e         = __builtin_amdgcn_readfirstlane(rp[node]);
    const int end = __builtin_amdgcn_readfirstlane(rp[node + 1]);
    constexpr int V = C / 64;
    float acc[V] = {};
    const unsigned short* fb = (const unsigned short*)feat;
    const unsigned loff = (unsigned)lane * V;

    for (; e + 8 <= end; e += 8) {
        int2 p[8];
#pragma unroll
        for (int j = 0; j < 8; ++j) p[j] = edges[e + j];
        if constexpr (V == 4) {
            ushort4 u[8];
#pragma unroll
            for (int j = 0; j < 8; ++j)
                u[j] = *(const ushort4*)(fb + (unsigned)p[j].x * C + loff);
#pragma unroll
            for (int j = 0; j < 8; ++j) {
                float w = __int_as_float(p[j].y);
                acc[0] = fmaf(bf2f(u[j].x), w, acc[0]);
                acc[1] = fmaf(bf2f(u[j].y), w, acc[1]);
                acc[2] = fmaf(bf2f(u[j].z), w, acc[2]);
                acc[3] = fmaf(bf2f(u[j].w), w, acc[3]);
            }
        } else {
            ushort2 u[8];
#pragma unroll
            for (int j = 0; j < 8; ++j)
                u[j] = *(const ushort2*)(fb + (unsigned)p[j].x * C + loff);
#pragma unroll
            for (int j = 0; j < 8; ++j) {
                float w = __int_as_float(p[j].y);
                acc[0] = fmaf(bf2f(u[j].x), w, acc[0]);
                acc[1] = fmaf(bf2f(u[j].y), w, acc[1]);
            }
        }
    }
    for (; e + 2 <= end; e += 2) {
        int2 p0 = edges[e], p1 = edges[e + 1];
        float w0 = __int_as_float(p0.y), w1 = __int_as_float(p1.y);
        if constexpr (V == 4) {
            ushort4 u0 = *(const ushort4*)(fb + (unsigned)p0.x * C + loff);
            ushort4 u1 = *(const ushort4*)(fb + (unsigned)p1.x * C + loff);
            acc[0] = fmaf(bf2f(u0.x), w0, fmaf(bf2f(u1.x), w1, acc[0]));
            acc[1] = fmaf(bf2f(u0.y), w0, fmaf(bf2f(u1.y), w1, acc[1]));
            acc[2] = fmaf(bf2f(u0.z), w0, fmaf(bf2f(u1.z), w1, acc[2]));
            acc[3] = fmaf(bf2f(u0.w), w0, fmaf(bf2f(u1.w), w1, acc[3]));
        } else {
            ushort2 u0 = *(const ushort2*)(fb + (unsigned)p0.x * C + loff);
            ushort2 u1 = *(const ushort2*)(fb + (unsigned)p1.x * C + loff);
            acc[0] = fmaf(bf2f(u0.x), w0, fmaf(bf2f(u1.x), w1, acc[0]));
            acc[1] = fmaf(bf2f(u0.y), w0, fmaf(bf2f(u1.y), w1, acc[1]));
        }
    }
    if (e < end) {
        int2 p = edges[e];
        float wt = __int_as_float(p.y);
        const unsigned short* fp = fb + (unsigned)p.x * C + loff;
        if constexpr (V == 4) {
            ushort4 u = *(const ushort4*)fp;
            acc[0] = fmaf(bf2f(u.x), wt, acc[0]);
            acc[1] = fmaf(bf2f(u.y), wt, acc[1]);
            acc[2] = fmaf(bf2f(u.z), wt, acc[2]);
            acc[3] = fmaf(bf2f(u.w), wt, acc[3]);
        } else {
            ushort2 u = *(const ushort2*)fp;
            acc[0] = fmaf(bf2f(u.x), wt, acc[0]);
            acc[1] = fmaf(bf2f(u.y), wt, acc[1]);
        }
    }
    __hip_bfloat16 o[V];
#pragma unroll
    for (int i = 0; i < V; ++i) o[i] = __float2bfloat16(acc[i]);
    if constexpr (V == 2)
        *(ushort2*)(agg + (size_t)node * C + loff) = *(ushort2*)o;
    else
        *(ushort4*)(agg + (size_t)node * C + loff) = *(ushort4*)o;
}

// ---- MFMA GEMM: C = relu(A0@W0 + A1@W1 + bias), NC=256, bf16 in/out -------
__global__ __launch_bounds__(256) void gemm_mfma(
    const __hip_bfloat16* __restrict__ A0, const __hip_bfloat16* __restrict__ A1,
    const __hip_bfloat16* __restrict__ W0T, const __hip_bfloat16* __restrict__ W1T,
    const float* __restrict__ bias,
    __hip_bfloat16* __restrict__ Cmat,
    int n, int K0, int K1)
{
    __shared__ __hip_bfloat16 Asl[128 * 64];
    __shared__ __hip_bfloat16 Bsl[128 * 64];
    const int bm = blockIdx.x >> 1;
    const int bn = blockIdx.x & 1;
    const int row0 = bm * 128, col0 = bn * 128;
    const int t = threadIdx.x, lane = t & 63, wid = t >> 6;
    const int wr = wid >> 1, wc = wid & 1;

    f32x4 acc[4][4] = {};

    for (int seg = 0; seg < 2; ++seg) {
        const __hip_bfloat16* A  = seg ? A1 : A0;
        const __hip_bfloat16* WT = seg ? W1T : W0T;
        const int K = seg ? K1 : K0;
        for (int k0 = 0; k0 < K; k0 += 64) {
#pragma unroll
            for (int i = 0; i < 4; ++i) {
                int idx = i * 256 + t;
                int r = idx >> 3, c = idx & 7;
                int gr = row0 + r; if (gr >= n) gr = n - 1;
                const __hip_bfloat16* srcA =
                    A + (size_t)gr * K + k0 + ((c ^ (r & 7)) << 3);
                __builtin_amdgcn_global_load_lds(
                    (const __attribute__((address_space(1))) void*)srcA,
                    (__attribute__((address_space(3))) void*)&Asl[idx * 8], 16, 0, 0);
                const __hip_bfloat16* srcB =
                    WT + (size_t)(col0 + r) * K + k0 + ((c ^ (r & 7)) << 3);
                __builtin_amdgcn_global_load_lds(
                    (const __attribute__((address_space(1))) void*)srcB,
                    (__attribute__((address_space(3))) void*)&Bsl[idx * 8], 16, 0, 0);
            }
            __syncthreads();
#pragma unroll
            for (int kh = 0; kh < 2; ++kh) {
                const int cchunk = kh * 4 + (lane >> 4);
                short8 af[4], bfr[4];
#pragma unroll
                for (int m = 0; m < 4; ++m) {
                    int r = wr * 64 + m * 16 + (lane & 15);
                    af[m] = *(const short8*)&Asl[r * 64 + ((cchunk ^ (r & 7)) << 3)];
                }
#pragma unroll
                for (int nn = 0; nn < 4; ++nn) {
                    int r = wc * 64 + nn * 16 + (lane & 15);
                    bfr[nn] = *(const short8*)&Bsl[r * 64 + ((cchunk ^ (r & 7)) << 3)];
                }
#pragma unroll
                for (int m = 0; m < 4; ++m)
#pragma unroll
                    for (int nn = 0; nn < 4; ++nn)
                        acc[m][nn] = __builtin_amdgcn_mfma_f32_16x16x32_bf16(
                            af[m], bfr[nn], acc[m][nn], 0, 0, 0);
            }
            __syncthreads();
        }
    }

#pragma unroll
    for (int nn = 0; nn < 4; ++nn) {
        int col = col0 + wc * 64 + nn * 16 + (lane & 15);
        float b = bias[col];
#pragma unroll
        for (int m = 0; m < 4; ++m) {
#pragma unroll
            for (int rg = 0; rg < 4; ++rg) {
                int row = row0 + wr * 64 + m * 16 + ((lane >> 4) * 4) + rg;
                if (row < n) {
                    float v = fmaxf(acc[m][nn][rg] + b, 0.f);
                    Cmat[(size_t)row * 256 + col] = __float2bfloat16(v);
                }
            }
        }
    }
}

// ---- head: out = log_softmax([x1|x2] @ w_lin + b_lin), MFMA fused ---------
__global__ __launch_bounds__(256) void head_mfma(
    const __hip_bfloat16* __restrict__ X1, const __hip_bfloat16* __restrict__ X2,
    const __hip_bfloat16* __restrict__ WLT,   // [2][64][256]
    const float* __restrict__ b_lin,
    float* __restrict__ out, int n)
{
    __shared__ __hip_bfloat16 Asl[128 * 64];
    __shared__ __hip_bfloat16 Bsl[64 * 64];
    const int row0 = blockIdx.x * 128;
    const int t = threadIdx.x, lane = t & 63, wid = t >> 6;

    f32x4 acc[2][4] = {};

    for (int seg = 0; seg < 2; ++seg) {
        const __hip_bfloat16* A  = seg ? X2 : X1;
        const __hip_bfloat16* WT = WLT + seg * 64 * 256;
        for (int k0 = 0; k0 < 256; k0 += 64) {
#pragma unroll
            for (int i = 0; i < 4; ++i) {
                int idx = i * 256 + t;
                int r = idx >> 3, c = idx & 7;
                int gr = row0 + r; if (gr >= n) gr = n - 1;
                const __hip_bfloat16* srcA =
                    A + (size_t)gr * 256 + k0 + ((c ^ (r & 7)) << 3);
                __builtin_amdgcn_global_load_lds(
                    (const __attribute__((address_space(1))) void*)srcA,
                    (__attribute__((address_space(3))) void*)&Asl[idx * 8], 16, 0, 0);
            }
#pragma unroll
            for (int i = 0; i < 2; ++i) {
                int idx = i * 256 + t;
                int r = idx >> 3, c = idx & 7;
                const __hip_bfloat16* srcB =
                    WT + (size_t)r * 256 + k0 + ((c ^ (r & 7)) << 3);
                __builtin_amdgcn_global_load_lds(
                    (const __attribute__((address_space(1))) void*)srcB,
                    (__attribute__((address_space(3))) void*)&Bsl[idx * 8], 16, 0, 0);
            }
            __syncthreads();
#pragma unroll
            for (int kh = 0; kh < 2; ++kh) {
                const int cchunk = kh * 4 + (lane >> 4);
                short8 af[2], bfr[4];
#pragma unroll
                for (int m = 0; m < 2; ++m) {
                    int r = wid * 32 + m * 16 + (lane & 15);
                    af[m] = *(const short8*)&Asl[r * 64 + ((cchunk ^ (r & 7)) << 3)];
                }
#pragma unroll
                for (int nn = 0; nn < 4; ++nn) {
                    int r = nn * 16 + (lane & 15);
                    bfr[nn] = *(const short8*)&Bsl[r * 64 + ((cchunk ^ (r & 7)) << 3)];
                }
#pragma unroll
                for (int m = 0; m < 2; ++m)
#pragma unroll
                    for (int nn = 0; nn < 4; ++nn)
                        acc[m][nn] = __builtin_amdgcn_mfma_f32_16x16x32_bf16(
                            af[m], bfr[nn], acc[m][nn], 0, 0, 0);
            }
            __syncthreads();
        }
    }

    const int cl = lane & 15;
    float bb[4];
#pragma unroll
    for (int nn = 0; nn < 4; ++nn) {
        int col = nn * 16 + cl;
        bb[nn] = (col < 40) ? b_lin[col] : 0.f;
    }
#pragma unroll
    for (int m = 0; m < 2; ++m) {
#pragma unroll
        for (int rg = 0; rg < 4; ++rg) {
            float v[4];
            float mx = -1e30f;
#pragma unroll
            for (int nn = 0; nn < 4; ++nn) {
                int col = nn * 16 + cl;
                v[nn] = acc[m][nn][rg] + bb[nn];
                if (col < 40) mx = fmaxf(mx, v[nn]);
            }
#pragma unroll
            for (int off = 1; off < 16; off <<= 1)
                mx = fmaxf(mx, __shfl_xor(mx, off, 64));
            float s = 0.f;
#pragma unroll
            for (int nn = 0; nn < 4; ++nn) {
                int col = nn * 16 + cl;
                if (col < 40) s += expf(v[nn] - mx);
            }
#pragma unroll
            for (int off = 1; off < 16; off <<= 1)
                s += __shfl_xor(s, off, 64);
            float ls = logf(s);
            int row = row0 + wid * 32 + m * 16 + ((lane >> 4) * 4) + rg;
            if (row < n) {
#pragma unroll
                for (int nn = 0; nn < 4; ++nn) {
                    int col = nn * 16 + cl;
                    if (col < 40)
                        out[(size_t)row * 40 + col] = v[nn] - mx - ls;
                }
            }
        }
    }
}

// ---------------------------------------------------------------------------
extern "C" void kernel_launch(void* const* d_in, const int* in_sizes, int n_in,
                              void* d_out, int out_size, void* d_ws, size_t ws_size,
                              hipStream_t stream)
{
    const float* x       = (const float*)d_in[0];
    const int*   ei      = (const int*)  d_in[1];
    const float* ew      = (const float*)d_in[2];
    const float* w1_rel  = (const float*)d_in[3];
    const float* b1      = (const float*)d_in[4];
    const float* w1_root = (const float*)d_in[5];
    const float* w2_rel  = (const float*)d_in[6];
    const float* b2      = (const float*)d_in[7];
    const float* w2_root = (const float*)d_in[8];
    const float* w_lin   = (const float*)d_in[9];
    const float* b_lin   = (const float*)d_in[10];
    float* out = (float*)d_out;

    const int N = in_sizes[0] / 128;   // 50000
    const int E = in_sizes[2];         // 800000

    auto align = [](char*& p, size_t bytes) {
        char* r = p;
        p += (bytes + 255) & ~(size_t)255;
        return r;
    };
    char* wp = (char*)d_ws;
    __hip_bfloat16* xb     = (__hip_bfloat16*)align(wp, (size_t)N * 128 * 2);
    __hip_bfloat16* agg1b  = (__hip_bfloat16*)align(wp, (size_t)N * 128 * 2);
    __hip_bfloat16* x1b    = (__hip_bfloat16*)align(wp, (size_t)N * 256 * 2);
    __hip_bfloat16* agg2b  = (__hip_bfloat16*)align(wp, (size_t)N * 256 * 2);
    __hip_bfloat16* x2b    = (__hip_bfloat16*)align(wp, (size_t)N * 256 * 2);
    __hip_bfloat16* w1relT  = (__hip_bfloat16*)align(wp, 256 * 128 * 2);
    __hip_bfloat16* w1rootT = (__hip_bfloat16*)align(wp, 256 * 128 * 2);
    __hip_bfloat16* w2relT  = (__hip_bfloat16*)align(wp, 256 * 256 * 2);
    __hip_bfloat16* w2rootT = (__hip_bfloat16*)align(wp, 256 * 256 * 2);
    __hip_bfloat16* wlinT   = (__hip_bfloat16*)align(wp, 2 * 64 * 256 * 2);
    int*   counts  = (int*)align(wp, (size_t)N * 4);
    int*   row_ptr = (int*)align(wp, (size_t)(N + 1) * 4);
    int*   cursor  = (int*)align(wp, (size_t)N * 4);
    int*   bsum    = (int*)align(wp, 256 * 4);
    int*   bpre    = (int*)align(wp, 256 * 4);
    int2*  edges   = (int2*)align(wp, (size_t)E * 8);

    const int eb = (E + 255) / 256;
    const int nb = (N + 255) / 256;   // 196 <= 256

    // fused prep: zero counts, then count + x->bf16 + weight transposes
    hipMemsetAsync(counts, 0, (size_t)N * 4, stream);
    const int NX8 = N * 128 / 8;       // 800000
    {
        long long total = (long long)E + NX8 + 229376;
        int blocks = (int)((total + 255) / 256);
        prep_all<<<blocks, 256, 0, stream>>>(
            ei, counts, E, x, xb, NX8,
            w1_rel, w1_root, w2_rel, w2_root, w_lin,
            w1relT, w1rootT, w2relT, w2rootT, wlinT);
    }
    scan_block_sums<<<nb, 256, 0, stream>>>(counts, bsum, N);
    scan_bsum<<<1, 256, 0, stream>>>(bsum, bpre, nb);
    scan_final<<<nb, 256, 0, stream>>>(counts, bpre, row_ptr, cursor, N, E);
    fill_kernel<<<eb, 256, 0, stream>>>(ei, ew, cursor, edges, E);

    const int gather_blocks = (N * 64 + 255) / 256;
    const int gemm_grid     = ((N + 127) / 128) * 2;
    const int head_grid     = (N + 127) / 128;

    // layer 1
    gather_bf16<128><<<gather_blocks, 256, 0, stream>>>(
        xb, edges, row_ptr, agg1b, N);
    gemm_mfma<<<gemm_grid, 256, 0, stream>>>(
        agg1b, xb, w1relT, w1rootT, b1, x1b, N, 128, 128);
    // layer 2
    gather_bf16<256><<<gather_blocks, 256, 0, stream>>>(
        x1b, edges, row_ptr, agg2b, N);
    gemm_mfma<<<gemm_grid, 256, 0, stream>>>(
        agg2b, x1b, w2relT, w2rootT, b2, x2b, N, 256, 256);
    // head
    head_mfma<<<head_grid, 256, 0, stream>>>(x1b, x2b, wlinT, b_lin, out, N);
}